// Round 3
// baseline (681.596 us; speedup 1.0000x reference)
//
#include <hip/hip_runtime.h>
#include <hip/hip_bf16.h>

#define N_NODES 50000
#define N_EDGES 800000
#define D_IN 128
#define D_HID 512
#define D_OUT 128
#define CAT_DIM 640   // D_IN + D_HID
#define CAP 64        // per-node edge-bucket capacity (Poisson(16): P(>=64) ~ 1e-20)
#define NCHUNK 16     // D_HID / 32 dim-chunks; 50000*32*2B = 3.2 MB fits 4 MiB per-XCD L2

typedef __attribute__((ext_vector_type(8))) short short8;
typedef __attribute__((ext_vector_type(4))) float floatx4;

__device__ __forceinline__ unsigned short f2bf(float f) {
    unsigned u = __float_as_uint(f);
    unsigned r = u + 0x7fffu + ((u >> 16) & 1u);   // RNE
    return (unsigned short)(r >> 16);
}

// ---- fused prep: cast X -> concat[:,0:128], transpose-cast both weights,
//      zero deg, detect int64-vs-int32 adjacency. Branch by blockIdx range. ----
#define PREP_CASTX_BLOCKS   6250   // 50000*32 threads / 256
#define PREP_FCW_BLOCKS      256   // 128*512 / 256
#define PREP_W2_BLOCKS       320   // 640*128 / 256
#define PREP_DEG_BLOCKS      196   // ceil(50000/256)
#define PREP_TOTAL_BLOCKS  (PREP_CASTX_BLOCKS + PREP_FCW_BLOCKS + PREP_W2_BLOCKS + PREP_DEG_BLOCKS + 1)

__global__ void prep_kernel(const float* __restrict__ X, const float* __restrict__ fcW,
                            const float* __restrict__ Wm, const int* __restrict__ adj,
                            unsigned short* __restrict__ concat,
                            unsigned short* __restrict__ fcwT,
                            unsigned short* __restrict__ WT,
                            int* __restrict__ deg, int* __restrict__ flag) {
    int b = blockIdx.x;
    if (b < PREP_CASTX_BLOCKS) {
        int tid = b * 256 + threadIdx.x;               // 50000*32
        int row = tid >> 5;
        int cg  = (tid & 31) * 4;
        float4 v = *(const float4*)(X + (size_t)row * D_IN + cg);
        unsigned short o[4] = { f2bf(v.x), f2bf(v.y), f2bf(v.z), f2bf(v.w) };
        *(unsigned long long*)(concat + (size_t)row * CAT_DIM + cg) = *(unsigned long long*)o;
        return;
    }
    b -= PREP_CASTX_BLOCKS;
    if (b < PREP_FCW_BLOCKS) {
        int idx = b * 256 + threadIdx.x;               // 128*512
        int k = idx >> 9;
        int n = idx & (D_HID - 1);
        fcwT[n * D_IN + k] = f2bf(fcW[idx]);
        return;
    }
    b -= PREP_FCW_BLOCKS;
    if (b < PREP_W2_BLOCKS) {
        int idx = b * 256 + threadIdx.x;               // 640*128
        int k = idx >> 7;
        int n = idx & (D_OUT - 1);
        WT[n * CAT_DIM + k] = f2bf(Wm[idx]);
        return;
    }
    b -= PREP_W2_BLOCKS;
    if (b < PREP_DEG_BLOCKS) {
        int idx = b * 256 + threadIdx.x;
        if (idx < N_NODES) deg[idx] = 0;
        return;
    }
    // detect block (1 block): int64 high words are all 0 (node ids < 2^31)
    __shared__ int nz;
    if (threadIdx.x == 0) nz = 0;
    __syncthreads();
    if (adj[2 * threadIdx.x + 1] != 0) atomicAdd(&nz, 1);
    __syncthreads();
    if (threadIdx.x == 0) *flag = (nz == 0) ? 2 : 1;   // 2 => int64 stride
}

// ---- bucket edges by src ----
__global__ void hist_kernel(const int* __restrict__ adj, const int* __restrict__ flag,
                            int* __restrict__ deg, int* __restrict__ edge_list) {
    int e = blockIdx.x * blockDim.x + threadIdx.x;
    if (e >= N_EDGES) return;
    int s = flag[0];
    int src = adj[(size_t)e * s];
    int trg = adj[((size_t)N_EDGES + e) * s];
    int pos = atomicAdd(&deg[src], 1);
    if (pos < CAP) edge_list[src * CAP + pos] = trg;
}

// ---- bf16 MFMA GEMM: C[MxN] = A[MxK] * Bt^T, Bt stored [N x K] row-major.
//      BM=128 fixed; BN selects wave layout: 128 -> 2x2 waves (64x64 tiles),
//      64 -> 4x1 waves (32x64 tiles).
//      OUT_MODE: 0 = fp32 row-major, 1 = bf16 row-major, 2 = bf16 dim-tiled
//      Ft[(col/32)*N_NODES*32 + row*32 + col%32] ----
template<int BN, int BIAS_RELU, int OUT_MODE>
__global__ __launch_bounds__(256)
void gemm_kernel(const unsigned short* __restrict__ A, int lda,
                 const unsigned short* __restrict__ Bt, int ldb,
                 const float* __restrict__ bias,
                 void* __restrict__ Cout, int ldc,
                 int M, int N, int K) {
    constexpr int BK = 32, PAD = 8;
    constexpr int WR = (BN == 128) ? 2 : 4;   // waves along M
    constexpr int WC = 4 / WR;                // waves along N
    constexpr int TM = 128 / WR;              // wave tile M (64 or 32)
    constexpr int TN = BN / WC;               // wave tile N (64)
    constexpr int FM = TM / 16;               // frags along M (4 or 2)
    constexpr int FN = TN / 16;               // frags along N (4)
    __shared__ unsigned short As[128][BK + PAD];
    __shared__ unsigned short Bs[BN][BK + PAD];
    int bm = blockIdx.y * 128, bn = blockIdx.x * BN;
    int tid = threadIdx.x;
    int lane = tid & 63, w = tid >> 6;
    int wm = (w / WC) * TM, wn = (w % WC) * TN;
    int q = lane >> 4, l16 = lane & 15;

    floatx4 acc[FM][FN] = {};
    int r0 = tid >> 2;          // 0..63
    int cg = (tid & 3) * 8;     // 0,8,16,24

    for (int k0 = 0; k0 < K; k0 += BK) {
        #pragma unroll
        for (int p = 0; p < 2; ++p) {
            int r = r0 + p * 64;
            int gr = bm + r;
            uint4 va;
            if (gr < M) va = *(const uint4*)(A + (size_t)gr * lda + k0 + cg);
            else        va = make_uint4(0u, 0u, 0u, 0u);
            *(uint4*)(&As[r][cg]) = va;
        }
        #pragma unroll
        for (int p = 0; p < BN / 64; ++p) {
            int r = r0 + p * 64;
            uint4 vb = *(const uint4*)(Bt + (size_t)(bn + r) * ldb + k0 + cg);
            *(uint4*)(&Bs[r][cg]) = vb;
        }
        __syncthreads();
        short8 af[FM], bf[FN];
        #pragma unroll
        for (int i = 0; i < FM; ++i)
            af[i] = *(const short8*)(&As[wm + i * 16 + l16][q * 8]);
        #pragma unroll
        for (int i = 0; i < FN; ++i)
            bf[i] = *(const short8*)(&Bs[wn + i * 16 + l16][q * 8]);
        #pragma unroll
        for (int mi = 0; mi < FM; ++mi)
            #pragma unroll
            for (int ni = 0; ni < FN; ++ni)
                acc[mi][ni] = __builtin_amdgcn_mfma_f32_16x16x32_bf16(af[mi], bf[ni], acc[mi][ni], 0, 0, 0);
        __syncthreads();
    }

    #pragma unroll
    for (int mi = 0; mi < FM; ++mi) {
        #pragma unroll
        for (int ni = 0; ni < FN; ++ni) {
            #pragma unroll
            for (int r = 0; r < 4; ++r) {
                int row = bm + wm + mi * 16 + q * 4 + r;
                int col = bn + wn + ni * 16 + l16;
                if (row < M) {
                    float v = acc[mi][ni][r];
                    if (BIAS_RELU) v = fmaxf(v + bias[col], 0.0f);
                    if (OUT_MODE == 0)
                        ((float*)Cout)[(size_t)row * ldc + col] = v;
                    else if (OUT_MODE == 1)
                        ((unsigned short*)Cout)[(size_t)row * ldc + col] = f2bf(v);
                    else
                        ((unsigned short*)Cout)[((size_t)(col >> 5) * N_NODES + row) * 32 + (col & 31)] = f2bf(v);
                }
            }
        }
    }
}

// ---- dim-chunked segment max: wave per (node, chunk); 16 lanes per edge,
//      4 edges in flight; chunk working set 3.2 MB stays L2-resident.
//      grid = (12500, NCHUNK): x-fastest dispatch phases chunks temporally. ----
__global__ __launch_bounds__(256)
void aggregate_chunk_kernel(const unsigned short* __restrict__ Ft,
                            const int* __restrict__ deg,
                            const int* __restrict__ el,
                            unsigned short* __restrict__ concat) {
    int wave = threadIdx.x >> 6;
    int lane = threadIdx.x & 63;
    int n = blockIdx.x * 4 + wave;        // 12500*4 = 50000 exactly
    int c = blockIdx.y;
    int sub = lane & 15;                  // dword (2 dims) within 64 B chunk line
    int grp = lane >> 4;                  // edge slot 0..3
    int d = __builtin_nontemporal_load(deg + n);
    d = d < CAP ? d : CAP;
    const int* eln = el + n * CAP;
    const unsigned* fbase = (const unsigned*)(Ft + (size_t)c * N_NODES * 32);
    float lo = 0.f, hi = 0.f;
    for (int b = 0; b < d; b += 4) {
        int e = b + grp;
        if (e < d) {
            int t = __builtin_nontemporal_load(eln + e);   // stream, don't evict chunk
            unsigned u = fbase[t * 16 + sub];              // L2-hot chunk line
            lo = fmaxf(lo, __uint_as_float(u << 16));
            hi = fmaxf(hi, __uint_as_float(u & 0xffff0000u));
        }
    }
    lo = fmaxf(lo, __shfl_xor(lo, 16, 64));
    hi = fmaxf(hi, __shfl_xor(hi, 16, 64));
    lo = fmaxf(lo, __shfl_xor(lo, 32, 64));
    hi = fmaxf(hi, __shfl_xor(hi, 32, 64));
    if (grp == 0) {
        unsigned out = (__float_as_uint(lo) >> 16) | (__float_as_uint(hi) & 0xffff0000u);
        ((unsigned*)(concat + (size_t)n * CAT_DIM + D_IN + c * 32))[sub] = out;
    }
}

extern "C" void kernel_launch(void* const* d_in, const int* in_sizes, int n_in,
                              void* d_out, int out_size, void* d_ws, size_t ws_size,
                              hipStream_t stream) {
    const float* X    = (const float*)d_in[0];
    const float* fc_w = (const float*)d_in[1];
    const float* fc_b = (const float*)d_in[2];
    const float* Wm   = (const float*)d_in[3];
    const int*   adj  = (const int*)d_in[4];

    char* ws = (char*)d_ws;
    size_t off = 0;
    auto alloc = [&](size_t bytes) -> void* {
        void* p = ws + off;
        off = (off + bytes + 255) & ~(size_t)255;
        return p;
    };
    unsigned short* concat = (unsigned short*)alloc((size_t)N_NODES * CAT_DIM * 2);
    unsigned short* Ft     = (unsigned short*)alloc((size_t)N_NODES * D_HID * 2);
    unsigned short* fcwT   = (unsigned short*)alloc((size_t)D_HID * D_IN * 2);
    unsigned short* WT     = (unsigned short*)alloc((size_t)D_OUT * CAT_DIM * 2);
    int* deg       = (int*)alloc((size_t)N_NODES * 4);
    int* edge_list = (int*)alloc((size_t)N_NODES * CAP * 4);
    int* flag      = (int*)alloc(256);

    prep_kernel<<<PREP_TOTAL_BLOCKS, 256, 0, stream>>>(X, fc_w, Wm, adj, concat, fcwT, WT, deg, flag);
    hist_kernel<<<(N_EDGES + 255) / 256, 256, 0, stream>>>(adj, flag, deg, edge_list);

    dim3 g1(D_HID / 128, (N_NODES + 127) / 128);
    gemm_kernel<128, 1, 2><<<g1, 256, 0, stream>>>(concat, CAT_DIM, fcwT, D_IN, fc_b,
                                                   Ft, 0, N_NODES, D_HID, D_IN);
    dim3 ga(N_NODES / 4, NCHUNK);
    aggregate_chunk_kernel<<<ga, 256, 0, stream>>>(Ft, deg, edge_list, concat);
    dim3 g2(D_OUT / 64, (N_NODES + 127) / 128);
    gemm_kernel<64, 0, 0><<<g2, 256, 0, stream>>>(concat, CAT_DIM, WT, CAT_DIM, nullptr,
                                                  d_out, D_OUT, N_NODES, D_OUT, CAT_DIM);
}

// Round 4
// 307.515 us; speedup vs baseline: 2.2165x; 2.2165x over previous
//
#include <hip/hip_runtime.h>
#include <hip/hip_bf16.h>

#define N_NODES 50000
#define N_EDGES 800000
#define D_IN 128
#define D_HID 512
#define D_OUT 128
#define CAT_DIM 640   // D_IN + D_HID
#define CAP 64        // per-node edge-bucket capacity (Poisson(16): P(>=64) ~ 1e-20)

typedef __attribute__((ext_vector_type(8))) short short8;
typedef __attribute__((ext_vector_type(4))) float floatx4;

__device__ __forceinline__ unsigned short f2bf(float f) {
    unsigned u = __float_as_uint(f);
    unsigned r = u + 0x7fffu + ((u >> 16) & 1u);   // RNE
    return (unsigned short)(r >> 16);
}

// ---- fused prep: cast X -> concat[:,0:128], transpose-cast both weights,
//      zero deg, detect int64-vs-int32 adjacency. Branch by blockIdx range. ----
#define PREP_CASTX_BLOCKS   6250   // 50000*32 threads / 256
#define PREP_FCW_BLOCKS      256   // 128*512 / 256
#define PREP_W2_BLOCKS       320   // 640*128 / 256
#define PREP_DEG_BLOCKS      196   // ceil(50000/256)
#define PREP_TOTAL_BLOCKS  (PREP_CASTX_BLOCKS + PREP_FCW_BLOCKS + PREP_W2_BLOCKS + PREP_DEG_BLOCKS + 1)

__global__ void prep_kernel(const float* __restrict__ X, const float* __restrict__ fcW,
                            const float* __restrict__ Wm, const int* __restrict__ adj,
                            unsigned short* __restrict__ concat,
                            unsigned short* __restrict__ fcwT,
                            unsigned short* __restrict__ WT,
                            int* __restrict__ deg, int* __restrict__ flag) {
    int b = blockIdx.x;
    if (b < PREP_CASTX_BLOCKS) {
        int tid = b * 256 + threadIdx.x;               // 50000*32
        int row = tid >> 5;
        int cg  = (tid & 31) * 4;
        float4 v = *(const float4*)(X + (size_t)row * D_IN + cg);
        unsigned short o[4] = { f2bf(v.x), f2bf(v.y), f2bf(v.z), f2bf(v.w) };
        *(unsigned long long*)(concat + (size_t)row * CAT_DIM + cg) = *(unsigned long long*)o;
        return;
    }
    b -= PREP_CASTX_BLOCKS;
    if (b < PREP_FCW_BLOCKS) {
        int idx = b * 256 + threadIdx.x;               // 128*512
        int k = idx >> 9;
        int n = idx & (D_HID - 1);
        fcwT[n * D_IN + k] = f2bf(fcW[idx]);
        return;
    }
    b -= PREP_FCW_BLOCKS;
    if (b < PREP_W2_BLOCKS) {
        int idx = b * 256 + threadIdx.x;               // 640*128
        int k = idx >> 7;
        int n = idx & (D_OUT - 1);
        WT[n * CAT_DIM + k] = f2bf(Wm[idx]);
        return;
    }
    b -= PREP_W2_BLOCKS;
    if (b < PREP_DEG_BLOCKS) {
        int idx = b * 256 + threadIdx.x;
        if (idx < N_NODES) deg[idx] = 0;
        return;
    }
    // detect block (1 block): int64 high words are all 0 (node ids < 2^31)
    __shared__ int nz;
    if (threadIdx.x == 0) nz = 0;
    __syncthreads();
    if (adj[2 * threadIdx.x + 1] != 0) atomicAdd(&nz, 1);
    __syncthreads();
    if (threadIdx.x == 0) *flag = (nz == 0) ? 2 : 1;   // 2 => int64 stride
}

// ---- bucket edges by src: 2 edges per thread, vectorized int64 path ----
__global__ void hist_kernel(const int* __restrict__ adj, const int* __restrict__ flag,
                            int* __restrict__ deg, int* __restrict__ edge_list) {
    int t = blockIdx.x * blockDim.x + threadIdx.x;
    int e0 = t * 2;
    if (e0 >= N_EDGES) return;
    int s = flag[0];
    int src0, src1, trg0, trg1;
    if (s == 2) {   // int64: edges e0,e0+1 -> adj dwords [2e0 .. 2e0+3], coalesced uint4
        int4 vs = *(const int4*)(adj + 2 * (size_t)e0);
        int4 vt = *(const int4*)(adj + 2 * ((size_t)N_EDGES + e0));
        src0 = vs.x; src1 = vs.z;
        trg0 = vt.x; trg1 = vt.z;
    } else {        // int32
        int2 vs = *(const int2*)(adj + e0);
        int2 vt = *(const int2*)(adj + N_EDGES + e0);
        src0 = vs.x; src1 = vs.y;
        trg0 = vt.x; trg1 = vt.y;
    }
    int p0 = atomicAdd(&deg[src0], 1);
    if (p0 < CAP) edge_list[src0 * CAP + p0] = trg0;
    int p1 = atomicAdd(&deg[src1], 1);
    if (p1 < CAP) edge_list[src1 * CAP + p1] = trg1;
}

// ---- bf16 MFMA GEMM: C[MxN] = A[MxK] * Bt^T, Bt stored [N x K] row-major.
//      2x2 wave layout; BM in {64,128}, BN in {64,128}. ----
template<int BM, int BN, int BIAS_RELU, int OUT_BF16>
__global__ __launch_bounds__(256)
void gemm_kernel(const unsigned short* __restrict__ A, int lda,
                 const unsigned short* __restrict__ Bt, int ldb,
                 const float* __restrict__ bias,
                 void* __restrict__ Cout, int ldc,
                 int M, int N, int K) {
    constexpr int BK = 32, PAD = 8;
    constexpr int TM = BM / 2;                // wave tile M
    constexpr int TN = BN / 2;                // wave tile N
    constexpr int FM = TM / 16;               // frags along M
    constexpr int FN = TN / 16;               // frags along N
    __shared__ unsigned short As[BM][BK + PAD];
    __shared__ unsigned short Bs[BN][BK + PAD];
    int bm = blockIdx.y * BM, bn = blockIdx.x * BN;
    int tid = threadIdx.x;
    int lane = tid & 63, w = tid >> 6;
    int wm = (w >> 1) * TM, wn = (w & 1) * TN;
    int q = lane >> 4, l16 = lane & 15;

    floatx4 acc[FM][FN] = {};
    int r0 = tid >> 2;          // 0..63
    int cg = (tid & 3) * 8;     // 0,8,16,24

    for (int k0 = 0; k0 < K; k0 += BK) {
        #pragma unroll
        for (int p = 0; p < BM / 64; ++p) {
            int r = r0 + p * 64;
            int gr = bm + r;
            uint4 va;
            if (gr < M) va = *(const uint4*)(A + (size_t)gr * lda + k0 + cg);
            else        va = make_uint4(0u, 0u, 0u, 0u);
            *(uint4*)(&As[r][cg]) = va;
        }
        #pragma unroll
        for (int p = 0; p < BN / 64; ++p) {
            int r = r0 + p * 64;
            uint4 vb = *(const uint4*)(Bt + (size_t)(bn + r) * ldb + k0 + cg);
            *(uint4*)(&Bs[r][cg]) = vb;
        }
        __syncthreads();
        short8 af[FM], bf[FN];
        #pragma unroll
        for (int i = 0; i < FM; ++i)
            af[i] = *(const short8*)(&As[wm + i * 16 + l16][q * 8]);
        #pragma unroll
        for (int i = 0; i < FN; ++i)
            bf[i] = *(const short8*)(&Bs[wn + i * 16 + l16][q * 8]);
        #pragma unroll
        for (int mi = 0; mi < FM; ++mi)
            #pragma unroll
            for (int ni = 0; ni < FN; ++ni)
                acc[mi][ni] = __builtin_amdgcn_mfma_f32_16x16x32_bf16(af[mi], bf[ni], acc[mi][ni], 0, 0, 0);
        __syncthreads();
    }

    #pragma unroll
    for (int mi = 0; mi < FM; ++mi) {
        #pragma unroll
        for (int ni = 0; ni < FN; ++ni) {
            #pragma unroll
            for (int r = 0; r < 4; ++r) {
                int row = bm + wm + mi * 16 + q * 4 + r;
                int col = bn + wn + ni * 16 + l16;
                if (row < M) {
                    float v = acc[mi][ni][r];
                    if (BIAS_RELU) v = fmaxf(v + bias[col], 0.0f);
                    if (OUT_BF16) ((unsigned short*)Cout)[(size_t)row * ldc + col] = f2bf(v);
                    else          ((float*)Cout)[(size_t)row * ldc + col] = v;
                }
            }
        }
    }
}

// ---- segment max: wave per node, lane owns 8 of 512 dims (Round-1 form) ----
__device__ __forceinline__ void fmax_bf16x8(float* acc, const uint4& p) {
    const unsigned* a = (const unsigned*)&p;
    #pragma unroll
    for (int j = 0; j < 4; ++j) {
        unsigned u = a[j];
        acc[2 * j]     = fmaxf(acc[2 * j],     __uint_as_float(u << 16));
        acc[2 * j + 1] = fmaxf(acc[2 * j + 1], __uint_as_float(u & 0xffff0000u));
    }
}

__global__ __launch_bounds__(256)
void aggregate_kernel(const unsigned short* __restrict__ F,
                      const int* __restrict__ deg,
                      const int* __restrict__ edge_list,
                      unsigned short* __restrict__ concat) {
    int gw = (blockIdx.x * 256 + threadIdx.x) >> 6;
    if (gw >= N_NODES) return;
    int lane = threadIdx.x & 63;
    int d = deg[gw];
    d = d < CAP ? d : CAP;
    const int* el = edge_list + gw * CAP;
    float acc[8] = {0.f, 0.f, 0.f, 0.f, 0.f, 0.f, 0.f, 0.f};
    int i = 0;
    for (; i + 2 <= d; i += 2) {
        int t0 = el[i], t1 = el[i + 1];
        uint4 p0 = *(const uint4*)(F + (size_t)t0 * D_HID + lane * 8);
        uint4 p1 = *(const uint4*)(F + (size_t)t1 * D_HID + lane * 8);
        fmax_bf16x8(acc, p0);
        fmax_bf16x8(acc, p1);
    }
    if (i < d) {
        int t0 = el[i];
        uint4 p0 = *(const uint4*)(F + (size_t)t0 * D_HID + lane * 8);
        fmax_bf16x8(acc, p0);
    }
    unsigned out[4];
    #pragma unroll
    for (int j = 0; j < 4; ++j) {
        unsigned lo = __float_as_uint(acc[2 * j]) >> 16;          // exact: maxima of bf16 values
        unsigned hi = __float_as_uint(acc[2 * j + 1]) & 0xffff0000u;
        out[j] = lo | hi;
    }
    *(uint4*)(concat + (size_t)gw * CAT_DIM + D_IN + lane * 8) = *(uint4*)out;
}

extern "C" void kernel_launch(void* const* d_in, const int* in_sizes, int n_in,
                              void* d_out, int out_size, void* d_ws, size_t ws_size,
                              hipStream_t stream) {
    const float* X    = (const float*)d_in[0];
    const float* fc_w = (const float*)d_in[1];
    const float* fc_b = (const float*)d_in[2];
    const float* Wm   = (const float*)d_in[3];
    const int*   adj  = (const int*)d_in[4];

    char* ws = (char*)d_ws;
    size_t off = 0;
    auto alloc = [&](size_t bytes) -> void* {
        void* p = ws + off;
        off = (off + bytes + 255) & ~(size_t)255;
        return p;
    };
    unsigned short* concat = (unsigned short*)alloc((size_t)N_NODES * CAT_DIM * 2);
    unsigned short* F      = (unsigned short*)alloc((size_t)N_NODES * D_HID * 2);
    unsigned short* fcwT   = (unsigned short*)alloc((size_t)D_HID * D_IN * 2);
    unsigned short* WT     = (unsigned short*)alloc((size_t)D_OUT * CAT_DIM * 2);
    int* deg       = (int*)alloc((size_t)N_NODES * 4);
    int* edge_list = (int*)alloc((size_t)N_NODES * CAP * 4);
    int* flag      = (int*)alloc(256);

    prep_kernel<<<PREP_TOTAL_BLOCKS, 256, 0, stream>>>(X, fc_w, Wm, adj, concat, fcwT, WT, deg, flag);
    hist_kernel<<<(N_EDGES / 2 + 255) / 256, 256, 0, stream>>>(adj, flag, deg, edge_list);

    dim3 g1(D_HID / 128, (N_NODES + 127) / 128);
    gemm_kernel<128, 128, 1, 1><<<g1, 256, 0, stream>>>(concat, CAT_DIM, fcwT, D_IN, fc_b,
                                                        F, D_HID, N_NODES, D_HID, D_IN);
    aggregate_kernel<<<(N_NODES * 64 + 255) / 256, 256, 0, stream>>>(F, deg, edge_list, concat);
    dim3 g2(D_OUT / 128, (N_NODES + 63) / 64);
    gemm_kernel<64, 128, 0, 0><<<g2, 256, 0, stream>>>(concat, CAT_DIM, WT, CAT_DIM, nullptr,
                                                       d_out, D_OUT, N_NODES, D_OUT, CAT_DIM);
}